// Round 6
// baseline (235.830 us; speedup 1.0000x reference)
//
#include <hip/hip_runtime.h>
#include <math.h>

typedef unsigned short u16;
typedef unsigned int   u32;

#define B_   16
#define C_   256
#define HW_  1024
#define N_   16384      // B*H*W rows
#define NE_  8192       // codebook entries
#define K_   256        // feature dim
#define NSPLIT 8
#define CPS  1024       // codes per split
#define NZQ  4194304    // B*C*H*W

typedef _Float16 f16x8 __attribute__((ext_vector_type(8)));
typedef float    f32x16 __attribute__((ext_vector_type(16)));

// output layout: [0, NZQ) = z_q (B,C,H,W); [NZQ] = loss; [NZQ+1, NZQ+1+N_) = indices (as float)

__device__ __forceinline__ u16 f2h(float x) {
    union { _Float16 h; u16 u; } c;
    c.h = (_Float16)x;
    return c.u;
}

// ---------------------------------------------------------------------------
// A: transpose z (B,C,HW) -> z_flat [N_, K_] fp32 + fp16
__global__ void k_transpose_z(const float* __restrict__ z, float* __restrict__ zf,
                              u16* __restrict__ zh) {
    __shared__ float tile[32][33];
    int b   = blockIdx.z;
    int hw0 = blockIdx.x * 32;
    int c0  = blockIdx.y * 32;
    int tx = threadIdx.x;   // 0..31
    int ty = threadIdx.y;   // 0..7
    #pragma unroll
    for (int i = 0; i < 4; ++i) {
        int c = c0 + ty + i * 8;
        tile[ty + i * 8][tx] = z[((size_t)b * C_ + c) * HW_ + hw0 + tx];
    }
    __syncthreads();
    #pragma unroll
    for (int i = 0; i < 4; ++i) {
        int hw = hw0 + ty + i * 8;
        size_t o = ((size_t)b * HW_ + hw) * C_ + c0 + tx;
        float v = tile[tx][ty + i * 8];
        zf[o] = v;
        zh[o] = f2h(v);
    }
}

// ---------------------------------------------------------------------------
// B: codebook GEMM: cb[n][c] = sum_d frozen[n][d] * w[c][d]; also fp16 copy
__global__ __launch_bounds__(256) void k_codebook_gemm(
        const float* __restrict__ f, const float* __restrict__ w,
        float* __restrict__ cb, u16* __restrict__ cbh) {
    __shared__ float Fs[16][68];
    __shared__ float Ws[16][68];
    int n0 = blockIdx.x * 64;
    int c0 = blockIdx.y * 64;
    int tid = threadIdx.x;
    int tx = tid & 15, ty = tid >> 4;
    int nl = tid >> 2;            // 0..63
    int kq = (tid & 3) * 4;       // 0,4,8,12
    float acc[4][4] = {};
    for (int kb = 0; kb < K_; kb += 16) {
        float4 fv = *(const float4*)&f[(size_t)(n0 + nl) * K_ + kb + kq];
        float4 wv = *(const float4*)&w[(size_t)(c0 + nl) * K_ + kb + kq];
        __syncthreads();
        Fs[kq + 0][nl] = fv.x; Fs[kq + 1][nl] = fv.y; Fs[kq + 2][nl] = fv.z; Fs[kq + 3][nl] = fv.w;
        Ws[kq + 0][nl] = wv.x; Ws[kq + 1][nl] = wv.y; Ws[kq + 2][nl] = wv.z; Ws[kq + 3][nl] = wv.w;
        __syncthreads();
        #pragma unroll
        for (int k = 0; k < 16; ++k) {
            float4 a = *(float4*)&Fs[k][ty * 4];
            float4 b = *(float4*)&Ws[k][tx * 4];
            float av[4] = {a.x, a.y, a.z, a.w};
            float bv[4] = {b.x, b.y, b.z, b.w};
            #pragma unroll
            for (int i = 0; i < 4; ++i)
                #pragma unroll
                for (int j = 0; j < 4; ++j)
                    acc[i][j] += av[i] * bv[j];
        }
    }
    #pragma unroll
    for (int i = 0; i < 4; ++i) {
        size_t o = (size_t)(n0 + ty * 4 + i) * K_ + c0 + tx * 4;
        *(float4*)&cb[o] = make_float4(acc[i][0], acc[i][1], acc[i][2], acc[i][3]);
        *(ushort4*)&cbh[o] = make_ushort4(f2h(acc[i][0]), f2h(acc[i][1]),
                                          f2h(acc[i][2]), f2h(acc[i][3]));
    }
}

// ---------------------------------------------------------------------------
// B2: c2d[n] = ||cb[n]||^2 exact (fp64, for rescore);
//     c2[n]  = 4096*||cb[n]||^2 + 262144  (pre-scaled for the scan's fixed-
//     point packed score: si = 4096*(score+64); score = c2 - 2 dot, |score|<40)
__global__ void k_c2(const float* __restrict__ cb, float* __restrict__ c2,
                     double* __restrict__ c2d) {
    int row  = blockIdx.x * 4 + (threadIdx.x >> 6);
    int lane = threadIdx.x & 63;
    float4 v = *(const float4*)&cb[(size_t)row * K_ + lane * 4];
    double s = (double)v.x * v.x + (double)v.y * v.y
             + (double)v.z * v.z + (double)v.w * v.w;
    #pragma unroll
    for (int off = 32; off; off >>= 1) s += __shfl_down(s, off, 64);
    if (lane == 0) { c2d[row] = s; c2[row] = (float)(s * 4096.0 + 262144.0); }
}

// ---------------------------------------------------------------------------
// C: fp16 MFMA distance scan — BARRIER-FREE main loop.
// Block 128 codes x 128 zrows; wave tile 64x64. z (B-operand) in registers
// (128 VGPR). Each wave stages its OWN 64-code x 64-k slice into a private
// depth-2 LDS ring (4 waves x 2 x 8KB): sync is intra-wave only —
// STAGE(s+1); s_waitcnt vmcnt(8); COMPUTE(s). No s_barrier in the loop, no
// sched fences -> waves drift and anti-phase; compiler pipelines freely.
// Buffer-reuse safety: same-wave program order + compiler lgkmcnt before
// MFMA use guarantees buf reads of step s complete before STAGE(s+2) issues.
// Epilogue: fixed-point packed score<<13 | code idx, branchless top-2.
__device__ __forceinline__ void ld_lds16(const void* g, void* l) {
    __builtin_amdgcn_global_load_lds((const __attribute__((address_space(1))) void*)g,
                                     (__attribute__((address_space(3))) void*)l, 16, 0, 0);
}

#define INS(M1, M2, U) { u32 t_ = min(M1, U); u32 h_ = max(M1, U); M1 = t_; M2 = min(M2, h_); }

// 16 scores from one 32x32 acc block: codes CGBASE+8h+j (j=r&3, h=r>>2).
// C2B holds 4096*c2+262144; si = sat_u32(C2B - 8192*dot) < 2^19.
#define SCORE16(ACC, M1, M2, CGBASE, C2B) do {                                    \
    u32 ib_ = (u32)(code0 + (CGBASE));                                            \
    _Pragma("unroll")                                                             \
    for (int h = 0; h < 4; ++h) {                                                 \
        float4 cv = *(const float4*)&(C2B)[(CGBASE) + 8 * h];                     \
        u32 u0 = (((u32)fmaf(-8192.f, (ACC)[4*h+0], cv.x)) << 13) + ib_ + 8*h + 0; \
        u32 u1 = (((u32)fmaf(-8192.f, (ACC)[4*h+1], cv.y)) << 13) + ib_ + 8*h + 1; \
        u32 u2 = (((u32)fmaf(-8192.f, (ACC)[4*h+2], cv.z)) << 13) + ib_ + 8*h + 2; \
        u32 u3 = (((u32)fmaf(-8192.f, (ACC)[4*h+3], cv.w)) << 13) + ib_ + 8*h + 3; \
        INS(M1, M2, u0); INS(M1, M2, u1); INS(M1, M2, u2); INS(M1, M2, u3);       \
    }                                                                             \
} while (0)

__global__ __launch_bounds__(256, 2) void k_scan_mfma(
        const u16* __restrict__ zh, const u16* __restrict__ cbh,
        const float* __restrict__ c2, int* __restrict__ t2i) {
    __shared__ __align__(16) u16 sW[4][2][4096];   // per-wave depth-2 ring (8KB each)
    __shared__ __align__(16) float c2s[1024];      // whole split's pre-scaled c2

    int r0    = blockIdx.x * 128;
    int split = blockIdx.y;
    int tid  = threadIdx.x;
    int wave = tid >> 6, lane = tid & 63;
    int l31 = lane & 31, q = lane >> 5;

    // ---- z rows in registers: rows (wave>>1)*64 + l31 (+32), q-half per 16-k slice
    const u16* zp = zh + (size_t)(r0 + ((wave >> 1) << 6) + l31) * K_ + q * 8;
    f16x8 zr0[16], zr1[16];
    #pragma unroll
    for (int t = 0; t < 16; ++t) {
        zr0[t] = *(const f16x8*)&zp[t * 16];
        zr1[t] = *(const f16x8*)&zp[32 * K_ + t * 16];
    }

    // ---- wave-private staging offsets: slot j covers 16B-units [j*64, j*64+64)
    // of the wave's 64-row x 64-k slice; unit idx = j*64+lane -> row r, col-unit u.
    // Pre-swizzled global source (involution u^(r&7)) + linear LDS dest.
    u32 go[8];   // u16 offsets within the wave's code slab
    #pragma unroll
    for (int j = 0; j < 8; ++j) {
        int idx = j * 64 + lane;
        int r = idx >> 3, u = idx & 7;
        go[j] = (u32)r * 256 + (u32)((u ^ (r & 7)) * 8);
    }

    u32 m1a = 0xFFFFFFFFu, m2a = 0xFFFFFFFFu;    // zrow base + l31
    u32 m1b = 0xFFFFFFFFu, m2b = 0xFFFFFFFFu;    // zrow base + 32 + l31

    // wave's code slab base: codes split*CPS + (wave&1)*64 + [0,64) rows
    const u16* cbW = cbh + ((size_t)split * CPS + ((wave & 1) << 6)) * K_;

    // stage K-step s (ct = s>>2 -> +ct*128 rows; kb = s&3 -> +kb*64 k) into ring s&1
    auto STAGE = [&](int s) {
        const u16* Ab = cbW + (size_t)(s >> 2) * (128 * K_) + (s & 3) * 64;
        u16* d = &sW[wave][s & 1][0];
        #pragma unroll
        for (int j = 0; j < 8; ++j) ld_lds16(Ab + go[j], d + j * 512);
    };

    f32x16 acc0 = (f32x16){}, acc1 = (f32x16){}, acc2 = (f32x16){}, acc3 = (f32x16){};

    auto COMPUTE = [&](int ct, int kb) {
        const u16* sAb = &sW[wave][kb & 1][0];
        __builtin_amdgcn_s_setprio(1);
        #pragma unroll
        for (int ks = 0; ks < 4; ++ks) {
            u32 u8 = (u32)(((ks * 2 + q) ^ (l31 & 7)) * 8);
            f16x8 af0 = *(const f16x8*)&sAb[(u32)l31 * 64 + u8];           // rows 0..31
            f16x8 af1 = *(const f16x8*)&sAb[(u32)l31 * 64 + 2048 + u8];    // rows 32..63
            acc0 = __builtin_amdgcn_mfma_f32_32x32x16_f16(af0, zr0[kb * 4 + ks], acc0, 0, 0, 0);
            acc1 = __builtin_amdgcn_mfma_f32_32x32x16_f16(af1, zr0[kb * 4 + ks], acc1, 0, 0, 0);
            acc2 = __builtin_amdgcn_mfma_f32_32x32x16_f16(af0, zr1[kb * 4 + ks], acc2, 0, 0, 0);
            acc3 = __builtin_amdgcn_mfma_f32_32x32x16_f16(af1, zr1[kb * 4 + ks], acc3, 0, 0, 0);
        }
        __builtin_amdgcn_s_setprio(0);
        if (kb == 3) {
            int code0 = split * CPS + ct * 128;
            const float* C2B = &c2s[ct * 128];
            int cga = ((wave & 1) << 6) + (q << 2);
            int cgb = cga + 32;
            SCORE16(acc0, m1a, m2a, cga, C2B);
            SCORE16(acc1, m1a, m2a, cgb, C2B);
            SCORE16(acc2, m1b, m2b, cga, C2B);
            SCORE16(acc3, m1b, m2b, cgb, C2B);
            acc0 = (f32x16){}; acc1 = (f32x16){}; acc2 = (f32x16){}; acc3 = (f32x16){};
        }
    };

    // prologue: stage step 0 + preload all c2; one drain+barrier (c2s visibility)
    STAGE(0);
    ld_lds16(&c2[split * CPS + wave * 256 + lane * 4], &c2s[wave * 256]);
    asm volatile("s_waitcnt vmcnt(0)" ::: "memory");
    __syncthreads();

    // barrier-free main loop: intra-wave counted vmcnt only
    for (int ct = 0; ct < 8; ++ct) {
        #pragma unroll
        for (int kb = 0; kb < 4; ++kb) {
            int s = ct * 4 + kb;
            if (s < 31) {
                STAGE(s + 1);
                asm volatile("s_waitcnt vmcnt(8)" ::: "memory");  // stage s retired
            } else {
                asm volatile("s_waitcnt vmcnt(0)" ::: "memory");  // tail drain
            }
            COMPUTE(ct, kb);
        }
    }

    // merge q-halves (lanes l <-> l^32): same zrow, complementary code subsets
    {
        u32 o1 = __shfl_xor(m1a, 32, 64), o2 = __shfl_xor(m2a, 32, 64);
        u32 h = max(m1a, o1); m1a = min(m1a, o1); m2a = min(min(m2a, o2), h);
        o1 = __shfl_xor(m1b, 32, 64); o2 = __shfl_xor(m2b, 32, 64);
        h = max(m1b, o1); m1b = min(m1b, o1); m2b = min(min(m2b, o2), h);
    }
    // cross-wave merge via recycled sW[0] — barrier FIRST (waves have drifted)
    __syncthreads();
    u32* mbuf = (u32*)&sW[0][0][0];   // [wave][zg][l31][2] = 512 u32
    if (q == 0) {
        int base = ((wave * 2 + 0) * 32 + l31) * 2;
        mbuf[base] = m1a; mbuf[base + 1] = m2a;
        base = ((wave * 2 + 1) * 32 + l31) * 2;
        mbuf[base] = m1b; mbuf[base + 1] = m2b;
    }
    __syncthreads();
    if (tid < 128) {
        int zr = tid, wp = zr >> 6, zg = (zr >> 5) & 1, l = zr & 31;
        int iA = (((wp * 2 + 0) * 2 + zg) * 32 + l) * 2;
        int iB = (((wp * 2 + 1) * 2 + zg) * 32 + l) * 2;
        u32 a1 = mbuf[iA], a2 = mbuf[iA + 1];
        u32 b1 = mbuf[iB], b2 = mbuf[iB + 1];
        u32 h  = max(a1, b1), f1 = min(a1, b1);
        u32 f2 = min(min(a2, b2), h);
        size_t o = ((size_t)split * N_ + (r0 + zr)) * 2;
        t2i[o] = (int)(f1 & 0x1FFFu);
        t2i[o + 1] = (int)(f2 & 0x1FFFu);
    }
}

// ---------------------------------------------------------------------------
// D: fp64 rescore of ALL 16 candidates/row. One wave per row (4 rows/wave
// serial); per candidate-pair the two 32-lane halves each read one cb row
// fully coalesced, butterfly-reduce, exchange via shfl_xor(32), ordered
// running-min with index tie-break. One barrier total.
__global__ __launch_bounds__(256) void k_finalize(
        const float* __restrict__ zf, const float* __restrict__ cb,
        const double* __restrict__ c2d, const int* __restrict__ t2i,
        float* __restrict__ out, float* __restrict__ partials) {
    __shared__ int   bidx[16];
    __shared__ float wsum[4];
    __shared__ float tile[16][260];
    int n0 = blockIdx.x * 16;
    int tid = threadIdx.x;
    int wv = tid >> 6, lane = tid & 63;
    int h = lane >> 5, l5 = lane & 31;

    for (int rr = 0; rr < 4; ++rr) {
        int n = n0 + wv * 4 + rr;
        double bs = 1e300; int bi = 0x7fffffff;
        for (int p = 0; p < 8; ++p) {
            int t = 2 * p + h;                 // candidate id 0..15
            int sp = t >> 1, wsel = t & 1;
            int ci = t2i[((size_t)sp * N_ + n) * 2 + wsel];
            double acc = 0.0;
            const float* zp = zf + (size_t)n * K_;
            const float* cp = cb + (size_t)ci * K_;
            #pragma unroll
            for (int jj = 0; jj < 2; ++jj) {
                float4 zv = *(const float4*)&zp[l5 * 4 + jj * 128];
                float4 cv = *(const float4*)&cp[l5 * 4 + jj * 128];
                acc += (double)zv.x * cv.x + (double)zv.y * cv.y
                     + (double)zv.z * cv.z + (double)zv.w * cv.w;
            }
            #pragma unroll
            for (int off = 1; off < 32; off <<= 1) acc += __shfl_xor(acc, off, 32);
            double sc = c2d[ci] - 2.0 * acc;
            double so = __shfl_xor(sc, 32, 64);
            int    io = __shfl_xor(ci, 32, 64);
            double s0 = h ? so : sc;  int i0 = h ? io : ci;   // cand 2p
            double s1 = h ? sc : so;  int i1 = h ? ci : io;   // cand 2p+1
            if (s0 < bs || (s0 == bs && i0 < bi)) { bs = s0; bi = i0; }
            if (s1 < bs || (s1 == bs && i1 < bi)) { bs = s1; bi = i1; }
        }
        if (lane == 0) {
            bidx[wv * 4 + rr] = bi;
            out[(size_t)NZQ + 1 + n] = (float)bi;   // indices output
        }
    }
    __syncthreads();

    // phase 2: gather + squared-error partial + stage for transposed write
    float accl = 0.f;
    for (int l = 0; l < 16; ++l) {
        int n = n0 + l;
        int bi = bidx[l];
        float zq = cb[(size_t)bi * K_ + tid];
        float d  = zf[(size_t)n * K_ + tid] - zq;
        accl += d * d;
        tile[l][tid] = zq;
    }
    #pragma unroll
    for (int off = 32; off; off >>= 1) accl += __shfl_down(accl, off, 64);
    if ((tid & 63) == 0) wsum[tid >> 6] = accl;
    __syncthreads();
    if (tid == 0) partials[blockIdx.x] = wsum[0] + wsum[1] + wsum[2] + wsum[3];
    // transposed write: out[(b*C + c)*HW + hw0 + l]
    int b = n0 >> 10, hw0 = n0 & 1023;
    #pragma unroll
    for (int g = 0; g < 4; ++g) {
        float4 v = make_float4(tile[g * 4 + 0][tid], tile[g * 4 + 1][tid],
                               tile[g * 4 + 2][tid], tile[g * 4 + 3][tid]);
        *(float4*)&out[((size_t)b * C_ + tid) * HW_ + hw0 + g * 4] = v;
    }
}

// ---------------------------------------------------------------------------
// E: loss = 1.25 * sum(partials) / (N*C)
__global__ void k_loss(const float* __restrict__ partials, float* __restrict__ out) {
    __shared__ double ws4[4];
    int tid = threadIdx.x;
    double s = 0.0;
    for (int i = tid; i < 1024; i += 256) s += (double)partials[i];
    #pragma unroll
    for (int off = 32; off; off >>= 1) s += __shfl_down(s, off, 64);
    if ((tid & 63) == 0) ws4[tid >> 6] = s;
    __syncthreads();
    if (tid == 0) {
        double tot = ws4[0] + ws4[1] + ws4[2] + ws4[3];
        out[NZQ] = (float)(1.25 * tot / (double)NZQ);
    }
}

// ---------------------------------------------------------------------------
extern "C" void kernel_launch(void* const* d_in, const int* in_sizes, int n_in,
                              void* d_out, int out_size, void* d_ws, size_t ws_size,
                              hipStream_t stream) {
    const float* z  = (const float*)d_in[0];
    const float* fc = (const float*)d_in[1];
    const float* wt = (const float*)d_in[2];
    float* out = (float*)d_out;

    float* ws = (float*)d_ws;
    const size_t OFF_ZF   = 0;                                   // N*K f
    const size_t OFF_CB   = OFF_ZF + (size_t)N_ * K_;            // NE*K f
    const size_t OFF_C2   = OFF_CB + (size_t)NE_ * K_;           // NE f
    const size_t OFF_C2D  = OFF_C2 + NE_;                        // NE d (2 f each)
    const size_t OFF_T2I  = OFF_C2D + (size_t)NE_ * 2;           // NSPLIT*N*2 i
    const size_t OFF_PART = OFF_T2I + (size_t)NSPLIT * N_ * 2;   // 1024 f
    const size_t OFF_ZH   = OFF_PART + 1024;                     // fp16 N*K
    const size_t OFF_CBH  = OFF_ZH + (size_t)N_ * K_ / 2;        // fp16 NE*K

    float*  zf   = ws + OFF_ZF;
    float*  cb   = ws + OFF_CB;
    float*  c2   = ws + OFF_C2;
    double* c2d  = (double*)(ws + OFF_C2D);
    int*    t2i  = (int*)(ws + OFF_T2I);
    float*  part = ws + OFF_PART;
    u16*    zh   = (u16*)(ws + OFF_ZH);
    u16*    cbh  = (u16*)(ws + OFF_CBH);

    k_transpose_z<<<dim3(HW_ / 32, C_ / 32, B_), dim3(32, 8), 0, stream>>>(z, zf, zh);
    k_codebook_gemm<<<dim3(NE_ / 64, K_ / 64), 256, 0, stream>>>(fc, wt, cb, cbh);
    k_c2<<<NE_ / 4, 256, 0, stream>>>(cb, c2, c2d);
    k_scan_mfma<<<dim3(N_ / 128, NSPLIT), 256, 0, stream>>>(zh, cbh, c2, t2i);
    k_finalize<<<N_ / 16, 256, 0, stream>>>(zf, cb, c2d, t2i, out, part);
    k_loss<<<1, 256, 0, stream>>>(part, out);
}

// Round 7
// 201.866 us; speedup vs baseline: 1.1682x; 1.1682x over previous
//
#include <hip/hip_runtime.h>
#include <math.h>

typedef unsigned short u16;
typedef unsigned int   u32;

#define B_   16
#define C_   256
#define HW_  1024
#define N_   16384      // B*H*W rows
#define NE_  8192       // codebook entries
#define K_   256        // feature dim
#define NSPLIT 4
#define CPS  2048       // codes per split
#define NZQ  4194304    // B*C*H*W

typedef _Float16 f16x8 __attribute__((ext_vector_type(8)));
typedef float    f32x16 __attribute__((ext_vector_type(16)));

// output layout: [0, NZQ) = z_q (B,C,H,W); [NZQ] = loss; [NZQ+1, NZQ+1+N_) = indices (as float)

__device__ __forceinline__ u16 f2h(float x) {
    union { _Float16 h; u16 u; } c;
    c.h = (_Float16)x;
    return c.u;
}

// ---------------------------------------------------------------------------
// A: transpose z (B,C,HW) -> z_flat [N_, K_] fp32 + fp16
__global__ void k_transpose_z(const float* __restrict__ z, float* __restrict__ zf,
                              u16* __restrict__ zh) {
    __shared__ float tile[32][33];
    int b   = blockIdx.z;
    int hw0 = blockIdx.x * 32;
    int c0  = blockIdx.y * 32;
    int tx = threadIdx.x;   // 0..31
    int ty = threadIdx.y;   // 0..7
    #pragma unroll
    for (int i = 0; i < 4; ++i) {
        int c = c0 + ty + i * 8;
        tile[ty + i * 8][tx] = z[((size_t)b * C_ + c) * HW_ + hw0 + tx];
    }
    __syncthreads();
    #pragma unroll
    for (int i = 0; i < 4; ++i) {
        int hw = hw0 + ty + i * 8;
        size_t o = ((size_t)b * HW_ + hw) * C_ + c0 + tx;
        float v = tile[tx][ty + i * 8];
        zf[o] = v;
        zh[o] = f2h(v);
    }
}

// ---------------------------------------------------------------------------
// B: codebook GEMM: cb[n][c] = sum_d frozen[n][d] * w[c][d]; also fp16 copy.
// Next-tile global loads issued BEFORE the compute phase (hides L2 latency).
__global__ __launch_bounds__(256) void k_codebook_gemm(
        const float* __restrict__ f, const float* __restrict__ w,
        float* __restrict__ cb, u16* __restrict__ cbh) {
    __shared__ float Fs[16][68];
    __shared__ float Ws[16][68];
    int n0 = blockIdx.x * 64;
    int c0 = blockIdx.y * 64;
    int tid = threadIdx.x;
    int tx = tid & 15, ty = tid >> 4;
    int nl = tid >> 2;            // 0..63
    int kq = (tid & 3) * 4;       // 0,4,8,12
    float acc[4][4] = {};
    float4 fv = *(const float4*)&f[(size_t)(n0 + nl) * K_ + kq];
    float4 wv = *(const float4*)&w[(size_t)(c0 + nl) * K_ + kq];
    for (int kb = 0; kb < K_; kb += 16) {
        __syncthreads();
        Fs[kq + 0][nl] = fv.x; Fs[kq + 1][nl] = fv.y; Fs[kq + 2][nl] = fv.z; Fs[kq + 3][nl] = fv.w;
        Ws[kq + 0][nl] = wv.x; Ws[kq + 1][nl] = wv.y; Ws[kq + 2][nl] = wv.z; Ws[kq + 3][nl] = wv.w;
        __syncthreads();
        if (kb + 16 < K_) {
            fv = *(const float4*)&f[(size_t)(n0 + nl) * K_ + kb + 16 + kq];
            wv = *(const float4*)&w[(size_t)(c0 + nl) * K_ + kb + 16 + kq];
        }
        #pragma unroll
        for (int k = 0; k < 16; ++k) {
            float4 a = *(float4*)&Fs[k][ty * 4];
            float4 b = *(float4*)&Ws[k][tx * 4];
            float av[4] = {a.x, a.y, a.z, a.w};
            float bv[4] = {b.x, b.y, b.z, b.w};
            #pragma unroll
            for (int i = 0; i < 4; ++i)
                #pragma unroll
                for (int j = 0; j < 4; ++j)
                    acc[i][j] += av[i] * bv[j];
        }
    }
    #pragma unroll
    for (int i = 0; i < 4; ++i) {
        size_t o = (size_t)(n0 + ty * 4 + i) * K_ + c0 + tx * 4;
        *(float4*)&cb[o] = make_float4(acc[i][0], acc[i][1], acc[i][2], acc[i][3]);
        *(ushort4*)&cbh[o] = make_ushort4(f2h(acc[i][0]), f2h(acc[i][1]),
                                          f2h(acc[i][2]), f2h(acc[i][3]));
    }
}

// ---------------------------------------------------------------------------
// B2: c2d[n] = ||cb[n]||^2 exact (fp64, for rescore);
//     c2[n]  = 4096*||cb[n]||^2 + 262144  (pre-scaled for the scan's fixed-
//     point packed score: si = 4096*(score+64); score = c2 - 2 dot, |score|<40)
__global__ void k_c2(const float* __restrict__ cb, float* __restrict__ c2,
                     double* __restrict__ c2d) {
    int row  = blockIdx.x * 4 + (threadIdx.x >> 6);
    int lane = threadIdx.x & 63;
    float4 v = *(const float4*)&cb[(size_t)row * K_ + lane * 4];
    double s = (double)v.x * v.x + (double)v.y * v.y
             + (double)v.z * v.z + (double)v.w * v.w;
    #pragma unroll
    for (int off = 32; off; off >>= 1) s += __shfl_down(s, off, 64);
    if (lane == 0) { c2d[row] = s; c2[row] = (float)(s * 4096.0 + 262144.0); }
}

// ---------------------------------------------------------------------------
// C: fp16 MFMA distance scan (R5 structure, best measured). Block 128 codes x
// 128 zrows; wave tile 64x64; z in registers (128 VGPR). A staged via 4-buffer
// LDS ring, depth-2 prefetch, counted vmcnt(8), raw s_barrier. NSPLIT=4 ->
// 16 code-tiles (64 K-steps) per block, 512 blocks = 2 block-instances/CU.
__device__ __forceinline__ void ld_lds16(const void* g, void* l) {
    __builtin_amdgcn_global_load_lds((const __attribute__((address_space(1))) void*)g,
                                     (__attribute__((address_space(3))) void*)l, 16, 0, 0);
}

#define INS(M1, M2, U) { u32 t_ = min(M1, U); u32 h_ = max(M1, U); M1 = t_; M2 = min(M2, h_); }

// 16 scores from one 32x32 acc block: codes CGBASE+8h+j (j=r&3, h=r>>2).
// C2B holds 4096*c2+262144; si = sat_u32(C2B - 8192*dot) < 2^19.
#define SCORE16(ACC, M1, M2, CGBASE, C2B) do {                                    \
    u32 ib_ = (u32)(code0 + (CGBASE));                                            \
    _Pragma("unroll")                                                             \
    for (int h = 0; h < 4; ++h) {                                                 \
        float4 cv = *(const float4*)&(C2B)[(CGBASE) + 8 * h];                     \
        u32 u0 = (((u32)fmaf(-8192.f, (ACC)[4*h+0], cv.x)) << 13) + ib_ + 8*h + 0; \
        u32 u1 = (((u32)fmaf(-8192.f, (ACC)[4*h+1], cv.y)) << 13) + ib_ + 8*h + 1; \
        u32 u2 = (((u32)fmaf(-8192.f, (ACC)[4*h+2], cv.z)) << 13) + ib_ + 8*h + 2; \
        u32 u3 = (((u32)fmaf(-8192.f, (ACC)[4*h+3], cv.w)) << 13) + ib_ + 8*h + 3; \
        INS(M1, M2, u0); INS(M1, M2, u1); INS(M1, M2, u2); INS(M1, M2, u3);       \
    }                                                                             \
} while (0)

#define WAITVM(N) { asm volatile("s_waitcnt vmcnt(" #N ")" ::: "memory"); \
                    __builtin_amdgcn_s_barrier();                          \
                    __builtin_amdgcn_sched_barrier(0); }

__global__ __launch_bounds__(256, 2) void k_scan_mfma(
        const u16* __restrict__ zh, const u16* __restrict__ cbh,
        const float* __restrict__ c2, int* __restrict__ t2i) {
    __shared__ __align__(16) u16 sA[4][8192];    // 4-step ring, 64KB total
    __shared__ __align__(16) float c2s[2048];    // whole split's pre-scaled c2 (8KB)

    int r0    = blockIdx.x * 128;
    int split = blockIdx.y;
    int tid  = threadIdx.x;
    int wave = tid >> 6, lane = tid & 63;
    int l31 = lane & 31, q = lane >> 5;
    int ra = ((wave & 1) << 6) + l31;            // A row base (codes)

    // ---- z rows in registers: rows (wave>>1)*64 + l31 (+32), q-half per 16-k slice
    const u16* zp = zh + (size_t)(r0 + ((wave >> 1) << 6) + l31) * K_ + q * 8;
    f16x8 zr0[16], zr1[16];
    #pragma unroll
    for (int t = 0; t < 16; ++t) {
        zr0[t] = *(const f16x8*)&zp[t * 16];
        zr1[t] = *(const f16x8*)&zp[32 * K_ + t * 16];
    }

    // ---- loop-invariant staging offsets (4 per thread)
    size_t ga[4]; u32 la[4];
    #pragma unroll
    for (int it = 0; it < 4; ++it) {
        int S = (it * 4 + wave) * 64 + lane;
        int row = S >> 3, u = S & 7;
        ga[it] = (size_t)row * K_ + (u ^ (row & 7)) * 8;
        la[it] = (u32)(it * 4 + wave) * 512;
    }

    u32 m1a = 0xFFFFFFFFu, m2a = 0xFFFFFFFFu;    // zrow base + l31
    u32 m1b = 0xFFFFFFFFu, m2b = 0xFFFFFFFFu;    // zrow base + 32 + l31

    const u16* cb0 = cbh + (size_t)split * CPS * K_;

    // stage K-step s (16KB of codes) into ring buffer s&3
    auto STAGE = [&](int s) {
        const u16* Ab = cb0 + (size_t)(s >> 2) * (128 * K_) + (s & 3) * 64;
        u16* d = &sA[s & 3][0];
        #pragma unroll
        for (int it = 0; it < 4; ++it) ld_lds16(Ab + ga[it], d + la[it]);
    };

    f32x16 acc0 = (f32x16){}, acc1 = (f32x16){}, acc2 = (f32x16){}, acc3 = (f32x16){};

    // compute K-step s = ct*4 + kb from ring buffer kb; epilogue at kb==3
    auto COMPUTE = [&](int ct, int kb) {
        const u16* sAb = &sA[kb][0];
        __builtin_amdgcn_s_setprio(1);
        #pragma unroll
        for (int ks = 0; ks < 4; ++ks) {
            u32 u8 = (u32)(((ks * 2 + q) ^ (l31 & 7)) * 8);
            f16x8 af0 = *(const f16x8*)&sAb[(u32)ra * 64 + u8];
            f16x8 af1 = *(const f16x8*)&sAb[(u32)ra * 64 + 2048 + u8];
            acc0 = __builtin_amdgcn_mfma_f32_32x32x16_f16(af0, zr0[kb * 4 + ks], acc0, 0, 0, 0);
            acc1 = __builtin_amdgcn_mfma_f32_32x32x16_f16(af1, zr0[kb * 4 + ks], acc1, 0, 0, 0);
            acc2 = __builtin_amdgcn_mfma_f32_32x32x16_f16(af0, zr1[kb * 4 + ks], acc2, 0, 0, 0);
            acc3 = __builtin_amdgcn_mfma_f32_32x32x16_f16(af1, zr1[kb * 4 + ks], acc3, 0, 0, 0);
        }
        __builtin_amdgcn_s_setprio(0);
        if (kb == 3) {
            int code0 = split * CPS + ct * 128;
            const float* C2B = &c2s[ct * 128];
            int cga = ((wave & 1) << 6) + (q << 2);
            int cgb = cga + 32;
            SCORE16(acc0, m1a, m2a, cga, C2B);
            SCORE16(acc1, m1a, m2a, cgb, C2B);
            SCORE16(acc2, m1b, m2b, cga, C2B);
            SCORE16(acc3, m1b, m2b, cgb, C2B);
            acc0 = (f32x16){}; acc1 = (f32x16){}; acc2 = (f32x16){}; acc3 = (f32x16){};
        }
    };

    // prologue: stage steps 0,1 + preload split's c2 (8KB, 2 chunks/wave); drain once
    STAGE(0); STAGE(1);
    ld_lds16(&c2[split * CPS + wave * 512 + lane * 4], &c2s[wave * 512]);
    ld_lds16(&c2[split * CPS + wave * 512 + 256 + lane * 4], &c2s[wave * 512 + 256]);
    asm volatile("s_waitcnt vmcnt(0)" ::: "memory");
    __builtin_amdgcn_s_barrier();
    __builtin_amdgcn_sched_barrier(0);

    // main: ct = 0..14 steady (stage s+2 <= 61), ct = 15 peeled tail
    for (int ct = 0; ct < 15; ++ct) {
        #pragma unroll
        for (int kb = 0; kb < 4; ++kb) {
            STAGE(ct * 4 + kb + 2);
            WAITVM(8);
            COMPUTE(ct, kb);
        }
    }
    STAGE(62); WAITVM(8); COMPUTE(15, 0);
    STAGE(63); WAITVM(8); COMPUTE(15, 1);
    WAITVM(4);            COMPUTE(15, 2);
    WAITVM(0);            COMPUTE(15, 3);

    // merge q-halves (lanes l <-> l^32): same zrow, complementary code subsets
    {
        u32 o1 = __shfl_xor(m1a, 32, 64), o2 = __shfl_xor(m2a, 32, 64);
        u32 h = max(m1a, o1); m1a = min(m1a, o1); m2a = min(min(m2a, o2), h);
        o1 = __shfl_xor(m1b, 32, 64); o2 = __shfl_xor(m2b, 32, 64);
        h = max(m1b, o1); m1b = min(m1b, o1); m2b = min(min(m2b, o2), h);
    }
    // cross-wave merge (code-halves) via recycled sA buffer 0 (all stages retired)
    u32* mbuf = (u32*)&sA[0][0];   // [wave][zg][l31][2] = 512 u32
    if (q == 0) {
        int base = ((wave * 2 + 0) * 32 + l31) * 2;
        mbuf[base] = m1a; mbuf[base + 1] = m2a;
        base = ((wave * 2 + 1) * 32 + l31) * 2;
        mbuf[base] = m1b; mbuf[base + 1] = m2b;
    }
    __syncthreads();
    if (tid < 128) {
        int zr = tid, wp = zr >> 6, zg = (zr >> 5) & 1, l = zr & 31;
        int iA = (((wp * 2 + 0) * 2 + zg) * 32 + l) * 2;
        int iB = (((wp * 2 + 1) * 2 + zg) * 32 + l) * 2;
        u32 a1 = mbuf[iA], a2 = mbuf[iA + 1];
        u32 b1 = mbuf[iB], b2 = mbuf[iB + 1];
        u32 h  = max(a1, b1), f1 = min(a1, b1);
        u32 f2 = min(min(a2, b2), h);
        size_t o = ((size_t)split * N_ + (r0 + zr)) * 2;
        t2i[o] = (int)(f1 & 0x1FFFu);
        t2i[o + 1] = (int)(f2 & 0x1FFFu);
    }
}

// ---------------------------------------------------------------------------
// D: fp64 rescore of 8 candidates/row (4 splits x top-2), software-pipelined:
// z row loaded ONCE into regs; all candidate indices + c2d prefetched; cb row
// for p+1 issued before compute of p. Two 32-lane halves each handle one
// candidate of the pair; butterfly-reduce; exchange via shfl_xor(32); ordered
// running-min with index tie-break (math bit-identical to previous rounds).
__global__ __launch_bounds__(256) void k_finalize(
        const float* __restrict__ zf, const float* __restrict__ cb,
        const double* __restrict__ c2d, const int* __restrict__ t2i,
        float* __restrict__ out, float* __restrict__ partials) {
    __shared__ int   bidx[16];
    __shared__ float wsum[4];
    __shared__ float tile[16][260];
    int n0 = blockIdx.x * 16;
    int tid = threadIdx.x;
    int wv = tid >> 6, lane = tid & 63;
    int h = lane >> 5, l5 = lane & 31;

    for (int rr = 0; rr < 4; ++rr) {
        int n = n0 + wv * 4 + rr;
        // z row once into registers
        const float* zp = zf + (size_t)n * K_;
        float4 za = *(const float4*)&zp[l5 * 4];
        float4 zb = *(const float4*)&zp[l5 * 4 + 128];
        // all candidate ids (this lane-half handles candidate 2p+h) + exact norms
        int cid[4];
        #pragma unroll
        for (int p = 0; p < 4; ++p)
            cid[p] = t2i[((size_t)p * N_ + n) * 2 + h];
        double c2p[4];
        #pragma unroll
        for (int p = 0; p < 4; ++p) c2p[p] = c2d[cid[p]];
        // prefetch first cb row
        float4 cva = *(const float4*)&cb[(size_t)cid[0] * K_ + l5 * 4];
        float4 cvb = *(const float4*)&cb[(size_t)cid[0] * K_ + l5 * 4 + 128];

        double bs = 1e300; int bi = 0x7fffffff;
        #pragma unroll
        for (int p = 0; p < 4; ++p) {
            float4 ca = cva, cbv = cvb;
            if (p < 3) {
                cva = *(const float4*)&cb[(size_t)cid[p + 1] * K_ + l5 * 4];
                cvb = *(const float4*)&cb[(size_t)cid[p + 1] * K_ + l5 * 4 + 128];
            }
            double acc = (double)za.x * ca.x + (double)za.y * ca.y
                       + (double)za.z * ca.z + (double)za.w * ca.w
                       + (double)zb.x * cbv.x + (double)zb.y * cbv.y
                       + (double)zb.z * cbv.z + (double)zb.w * cbv.w;
            #pragma unroll
            for (int off = 1; off < 32; off <<= 1) acc += __shfl_xor(acc, off, 32);
            double sc = c2p[p] - 2.0 * acc;
            int    ci = cid[p];
            double so = __shfl_xor(sc, 32, 64);
            int    io = __shfl_xor(ci, 32, 64);
            double s0 = h ? so : sc;  int i0 = h ? io : ci;   // cand 2p
            double s1 = h ? sc : so;  int i1 = h ? ci : io;   // cand 2p+1
            if (s0 < bs || (s0 == bs && i0 < bi)) { bs = s0; bi = i0; }
            if (s1 < bs || (s1 == bs && i1 < bi)) { bs = s1; bi = i1; }
        }
        if (lane == 0) {
            bidx[wv * 4 + rr] = bi;
            out[(size_t)NZQ + 1 + n] = (float)bi;   // indices output
        }
    }
    __syncthreads();

    // phase 2: gather + squared-error partial + stage for transposed write
    float accl = 0.f;
    for (int l = 0; l < 16; ++l) {
        int n = n0 + l;
        int bi = bidx[l];
        float zq = cb[(size_t)bi * K_ + tid];
        float d  = zf[(size_t)n * K_ + tid] - zq;
        accl += d * d;
        tile[l][tid] = zq;
    }
    #pragma unroll
    for (int off = 32; off; off >>= 1) accl += __shfl_down(accl, off, 64);
    if ((tid & 63) == 0) wsum[tid >> 6] = accl;
    __syncthreads();
    if (tid == 0) partials[blockIdx.x] = wsum[0] + wsum[1] + wsum[2] + wsum[3];
    // transposed write: out[(b*C + c)*HW + hw0 + l]
    int b = n0 >> 10, hw0 = n0 & 1023;
    #pragma unroll
    for (int g = 0; g < 4; ++g) {
        float4 v = make_float4(tile[g * 4 + 0][tid], tile[g * 4 + 1][tid],
                               tile[g * 4 + 2][tid], tile[g * 4 + 3][tid]);
        *(float4*)&out[((size_t)b * C_ + tid) * HW_ + hw0 + g * 4] = v;
    }
}

// ---------------------------------------------------------------------------
// E: loss = 1.25 * sum(partials) / (N*C)
__global__ void k_loss(const float* __restrict__ partials, float* __restrict__ out) {
    __shared__ double ws4[4];
    int tid = threadIdx.x;
    double s = 0.0;
    for (int i = tid; i < 1024; i += 256) s += (double)partials[i];
    #pragma unroll
    for (int off = 32; off; off >>= 1) s += __shfl_down(s, off, 64);
    if ((tid & 63) == 0) ws4[tid >> 6] = s;
    __syncthreads();
    if (tid == 0) {
        double tot = ws4[0] + ws4[1] + ws4[2] + ws4[3];
        out[NZQ] = (float)(1.25 * tot / (double)NZQ);
    }
}

// ---------------------------------------------------------------------------
extern "C" void kernel_launch(void* const* d_in, const int* in_sizes, int n_in,
                              void* d_out, int out_size, void* d_ws, size_t ws_size,
                              hipStream_t stream) {
    const float* z  = (const float*)d_in[0];
    const float* fc = (const float*)d_in[1];
    const float* wt = (const float*)d_in[2];
    float* out = (float*)d_out;

    float* ws = (float*)d_ws;
    const size_t OFF_ZF   = 0;                                   // N*K f
    const size_t OFF_CB   = OFF_ZF + (size_t)N_ * K_;            // NE*K f
    const size_t OFF_C2   = OFF_CB + (size_t)NE_ * K_;           // NE f
    const size_t OFF_C2D  = OFF_C2 + NE_;                        // NE d (2 f each)
    const size_t OFF_T2I  = OFF_C2D + (size_t)NE_ * 2;           // NSPLIT*N*2 i
    const size_t OFF_PART = OFF_T2I + (size_t)NSPLIT * N_ * 2;   // 1024 f
    const size_t OFF_ZH   = OFF_PART + 1024;                     // fp16 N*K
    const size_t OFF_CBH  = OFF_ZH + (size_t)N_ * K_ / 2;        // fp16 NE*K

    float*  zf   = ws + OFF_ZF;
    float*  cb   = ws + OFF_CB;
    float*  c2   = ws + OFF_C2;
    double* c2d  = (double*)(ws + OFF_C2D);
    int*    t2i  = (int*)(ws + OFF_T2I);
    float*  part = ws + OFF_PART;
    u16*    zh   = (u16*)(ws + OFF_ZH);
    u16*    cbh  = (u16*)(ws + OFF_CBH);

    k_transpose_z<<<dim3(HW_ / 32, C_ / 32, B_), dim3(32, 8), 0, stream>>>(z, zf, zh);
    k_codebook_gemm<<<dim3(NE_ / 64, K_ / 64), 256, 0, stream>>>(fc, wt, cb, cbh);
    k_c2<<<NE_ / 4, 256, 0, stream>>>(cb, c2, c2d);
    k_scan_mfma<<<dim3(N_ / 128, NSPLIT), 256, 0, stream>>>(zh, cbh, c2, t2i);
    k_finalize<<<N_ / 16, 256, 0, stream>>>(zf, cb, c2d, t2i, out, part);
    k_loss<<<1, 256, 0, stream>>>(part, out);
}